// Round 20
// baseline (219.550 us; speedup 1.0000x reference)
//
#include <hip/hip_runtime.h>
#include <hip/hip_bf16.h>

typedef unsigned short u16;
typedef unsigned int u32;
typedef __bf16 bf16x8 __attribute__((ext_vector_type(8)));
typedef float f32x4 __attribute__((ext_vector_type(4)));

#define AS1(p) ((const __attribute__((address_space(1))) void*)(p))
#define AS3(p) ((__attribute__((address_space(3))) void*)(p))

#define TOK   256
#define CDIM  512
#define QKVC  1536
#define LOG2E 1.4426950408889634f
#define QSCALE (0.17677669529663687f * 1.4426950408889634f)  // D^-0.5 * log2e

__device__ __forceinline__ u16 f2b(float f) {
  unsigned u = __float_as_uint(f);
  unsigned r = (u + 0x7fffu + ((u >> 16) & 1u)) >> 16;
  return (u16)r;
}
__device__ __forceinline__ u16 f2bc(float f) {
  __bf16 h = (__bf16)f;
  u16 u;
  __builtin_memcpy(&u, &h, 2);
  return u;
}
__device__ __forceinline__ float bf_lo(u32 wd) { return __uint_as_float(wd << 16); }
__device__ __forceinline__ float bf_hi(u32 wd) { return __uint_as_float(wd & 0xffff0000u); }
__device__ __forceinline__ float ex2(float x) {
  float r;
  asm("v_exp_f32 %0, %1" : "=v"(r) : "v"(x));
  return r;
}

// ---------------- fused preamble: weight cvt + bias2 + mod2 tables ----------------
__global__ __launch_bounds__(256) void prep_kernel(const float* __restrict__ qkv_w,
                                                   const float* __restrict__ proj_w,
                                                   const float* __restrict__ rpb,
                                                   u16* __restrict__ qkvwb,
                                                   u16* __restrict__ projwb,
                                                   u16* __restrict__ bias2,
                                                   u16* __restrict__ mod2) {
  const int blk = blockIdx.x, tid = threadIdx.x;
  if (blk < 512) {
    const float* in = (blk < 384) ? qkv_w : proj_w;
    u16* out = (blk < 384) ? qkvwb : projwb;
    int base = (blk < 384) ? blk : (blk - 384);
    int i = (base * 256 + tid) * 8;
    float4 a = *(const float4*)(in + i);
    float4 b = *(const float4*)(in + i + 4);
    u16 h[8];
    h[0] = f2b(a.x); h[1] = f2b(a.y); h[2] = f2b(a.z); h[3] = f2b(a.w);
    h[4] = f2b(b.x); h[5] = f2b(b.y); h[6] = f2b(b.z); h[7] = f2b(b.w);
    *(uint4*)(out + i) = *(const uint4*)h;
  } else if (blk < 4608) {
    int i = (blk - 512) * 256 + tid;   // 16*16*64*64 = 2^20
    int tr = i & 63, lane = (i >> 6) & 63, rb = (i >> 12) & 15, h = i >> 16;
    int t = tr >> 2, r = tr & 3;
    int n = rb * 16 + (lane & 15);
    int m = t * 16 + (lane >> 4) * 4 + r;
    int idx = ((n >> 4) - (m >> 4) + 15) * 31 + ((n & 15) - (m & 15) + 15);
    bias2[i] = f2b(rpb[idx * 16 + h] * LOG2E);
  } else {
    int i = (blk - 4608) * 256 + tid;  // 16*64*64 = 65536
    int tr = i & 63, lane = (i >> 6) & 63, rb = i >> 12;
    int t = tr >> 2, r = tr & 3;
    int n = rb * 16 + (lane & 15);
    int m = t * 16 + (lane >> 4) * 4 + r;
    int dr = (n >> 4) - (m >> 4), dc = (n & 15) - (m & 15);
    int d2 = dr * dr + dc * dc;
    float val = 0.0f;
    if (d2 <= 229) {   // exact integer form of (m >= bound); boundary at d2==229
      const float fc = 6.2831853071795864f / (60.0f * 1.4142135623730951f);
      val = expf(cosf(fc * sqrtf((float)d2))) * 0.5f;
    }
    mod2[i] = f2b(val);
  }
}

// ---------------- bf16 GEMM: out = A[M,K] @ Bt[N,K]^T + bias ----------------
// MODE 0: BM=256, 512 thr, 48KB LDS; A = x (fp32, converted in reg-staging);
//         two-shift LDS-bounce epilogue (waves 0-3 then 4-7 share 4 x 8KB tiles)
//         -> qfrag (scaled) / kfrag / vsw, fragment-ordered bf16.
// MODE 1: BM=128, 256 thr, A = attnb (bf16, gload_lds); f32 out (nontemporal).
template<int MODE>
__global__ __launch_bounds__(MODE == 0 ? 512 : 256) void gemm_bt(
    const float* __restrict__ Ax, const u16* __restrict__ A,
    const u16* __restrict__ Bt, const float* __restrict__ bvec,
    u16* __restrict__ oq, u16* __restrict__ ok, u16* __restrict__ ov,
    float* __restrict__ of) {
  constexpr int K = 512;
  constexpr int BM = (MODE == 0) ? 256 : 128;
  constexpr int NT = (MODE == 0) ? 512 : 256;
  constexpr int NBN = (MODE == 0) ? 12 : 4;
  constexpr int PER_XCD = (MODE == 0) ? 192 : 128;
  // MODE0: 48KB total (As 32KB + Bs 16KB); epilogue two-shifts inside dead As.
  __shared__ __align__(16) u16 SM[(MODE == 0) ? 24576 : 16384];
  u16* As = SM;
  u16* Bs = SM + BM * 64;
  const int tid = threadIdx.x, lane = tid & 63, w = tid >> 6;
  const int wr = w >> 1, wc = w & 1, lr = lane & 15, lg = lane >> 4;
  // XCD-chunked 1-D grid: bm-pair x all-bn contiguous per XCD (A+B L2-resident)
  const int logical = (blockIdx.x & 7) * PER_XCD + (blockIdx.x >> 3);
  const int bm = (logical / (2 * NBN)) * 2 + (logical & 1);
  const int bn = (logical % (2 * NBN)) >> 1;
  const u16* Bg = Bt + (size_t)bn * 128 * K;
  f32x4 acc[4][4];
#pragma unroll
  for (int m = 0; m < 4; ++m)
#pragma unroll
    for (int n = 0; n < 4; ++n) acc[m][n] = (f32x4){0.f, 0.f, 0.f, 0.f};

  for (int k0 = 0; k0 < K; k0 += 64) {
    if (MODE == 0) {
      // A: reg-stage fp32 x -> cvt -> swizzled ds_write (slot kc holds granule kc^(r&7))
#pragma unroll
      for (int it = 0; it < 4; ++it) {
        int chunk = it * NT + tid;            // (r, kc): r = chunk>>3, kc = chunk&7
        int r = chunk >> 3, kc = chunk & 7;
        int gg = kc ^ (r & 7);                // global granule for this LDS slot
        const float* src = Ax + (size_t)(bm * 256 + r) * K + k0 + gg * 8;
        float4 v0 = *(const float4*)src;
        float4 v1 = *(const float4*)(src + 4);
        u16 hb[8];
        hb[0] = f2bc(v0.x); hb[1] = f2bc(v0.y); hb[2] = f2bc(v0.z); hb[3] = f2bc(v0.w);
        hb[4] = f2bc(v1.x); hb[5] = f2bc(v1.y); hb[6] = f2bc(v1.z); hb[7] = f2bc(v1.w);
        *(uint4*)(As + chunk * 8) = *(const uint4*)hb;
      }
      // B: gload_lds with pre-swizzled source granule
#pragma unroll
      for (int it = 0; it < 2; ++it) {
        int chunk = it * NT + tid;
        int r = chunk >> 3, kc = chunk & 7;
        int kcs = kc ^ (r & 7);
        __builtin_amdgcn_global_load_lds(AS1(Bg + (size_t)r * K + k0 + kcs * 8),
                                         AS3(Bs + chunk * 8), 16, 0, 0);
      }
    } else {
      const u16* Ag = A + (size_t)bm * 128 * K;
#pragma unroll
      for (int it = 0; it < 4; ++it) {
        int chunk = it * NT + tid;
        int r = chunk >> 3, kc = chunk & 7;
        int kcs = kc ^ (r & 7);
        __builtin_amdgcn_global_load_lds(AS1(Ag + (size_t)r * K + k0 + kcs * 8),
                                         AS3(As + chunk * 8), 16, 0, 0);
        __builtin_amdgcn_global_load_lds(AS1(Bg + (size_t)r * K + k0 + kcs * 8),
                                         AS3(Bs + chunk * 8), 16, 0, 0);
      }
    }
    __syncthreads();
#pragma unroll
    for (int kk = 0; kk < 2; ++kk) {
      bf16x8 a[4], b[4];
#pragma unroll
      for (int m = 0; m < 4; ++m) {
        int ar = wr * 64 + m * 16 + lr;
        a[m] = *(const bf16x8*)&As[ar * 64 + (((kk * 4 + lg) ^ (lr & 7)) << 3)];
      }
#pragma unroll
      for (int n = 0; n < 4; ++n) {
        int br = wc * 64 + n * 16 + lr;
        b[n] = *(const bf16x8*)&Bs[br * 64 + (((kk * 4 + lg) ^ (lr & 7)) << 3)];
      }
#pragma unroll
      for (int m = 0; m < 4; ++m)
#pragma unroll
        for (int n = 0; n < 4; ++n)
          acc[m][n] = __builtin_amdgcn_mfma_f32_16x16x32_bf16(a[m], b[n], acc[m][n], 0, 0, 0);
    }
    __syncthreads();
  }

  if (MODE == 1) {
#pragma unroll
    for (int m = 0; m < 4; ++m)
#pragma unroll
      for (int n = 0; n < 4; ++n)
#pragma unroll
        for (int r = 0; r < 4; ++r) {
          int row = bm * BM + wr * 64 + m * 16 + lg * 4 + r;
          int col = bn * 128 + wc * 64 + n * 16 + lr;
          __builtin_nontemporal_store(acc[m][n][r] + bvec[col],
                                      &of[(size_t)row * CDIM + col]);
        }
    return;
  }

  // ---- MODE 0 epilogue: two-shift bounce via 4 shared 8KB swizzled wave tiles ----
  const int typ = bn >> 2;                 // 0=Q, 1=K, 2=V
  const int col0 = bn * 128 + wc * 64;
  const int row0 = bm * 256 + wr * 64;
  char* Tb = (char*)SM + (w & 3) * 8192;   // 4 tiles inside dead staging region

#pragma unroll
  for (int shift = 0; shift < 2; ++shift) {
    if ((w >> 2) == shift) {
#pragma unroll
      for (int n = 0; n < 4; ++n) {
        float bv = bvec[col0 + n * 16 + lr];
#pragma unroll
        for (int m = 0; m < 4; ++m)
#pragma unroll
          for (int r = 0; r < 4; ++r) {
            float v = acc[m][n][r] + bv;
            if (typ == 0) v *= QSCALE;
            int row_l, col_l;
            if (typ < 2) { row_l = m * 16 + lg * 4 + r; col_l = n * 16 + lr; }
            else         { row_l = n * 16 + lr;         col_l = m * 16 + lg * 4 + r; }  // V: transposed
            int byte = row_l * 128 + ((((col_l >> 3) ^ (row_l & 7)) << 4) | ((col_l & 7) << 1));
            *(u16*)(Tb + byte) = f2b(v);
          }
      }
      asm volatile("" ::: "memory");   // pin LDS write->read order (strict-aliasing guard)
      // wave-local tile: DS pipe is in-order within a wave; no barrier needed
      if (typ < 2) {
        // Q/K readback: lane = token row; 8 x {ds_read_b128, coalesced 16B store}
        int tok = row0 + lane;
        int tokb = tok >> 8;
        u16* obase = (typ == 0) ? oq : ok;
#pragma unroll
        for (int G = 0; G < 8; ++G) {
          int hl = G >> 2, q = G & 3;
          uint4 v = *(const uint4*)(Tb + lane * 128 + ((G ^ (lane & 7)) << 4));
          int hh = ((col0 >> 5) & 15) + hl;     // head index
          size_t a = ((((size_t)tokb * 16 + hh) * 16 + ((tok >> 4) & 15)) * 64 +
                      ((tok & 15) | (q << 4))) * 8;
          *(uint4*)(obase + a) = v;
        }
      } else {
        // V readback: transposed tile; swizzles cancel -> sequential granules
        int tl0 = row0 & 255, tokb = row0 >> 8;
        int hl = lane >> 5, t = (lane >> 3) & 3, c = lane & 7;
        int hh = ((col0 >> 5) & 15) + hl;       // head index
#pragma unroll
        for (int i = 0; i < 8; ++i) {
          int d = i * 4 + t;
          uint4 v = *(const uint4*)(Tb + (hl * 32 + d) * 128 + (c << 4));
          size_t a = (((size_t)tokb * 16 + hh) * 32 + d) * 256 + tl0 + c * 8;
          *(uint4*)(ov + a) = v;
        }
      }
    }
    __syncthreads();   // shift 0 readback complete before shift 1 overwrites tiles
  }
}

// ---------------- fused attention: 512-thread block = (b, h, qpair), 8 waves ----------------
__global__ __launch_bounds__(512, 4) void attn_kernel(const u16* __restrict__ qfrag,
                                                      const u16* __restrict__ kfrag,
                                                      const u16* __restrict__ vsw,
                                                      const u16* __restrict__ bias2,
                                                      const u16* __restrict__ mod2,
                                                      u16* __restrict__ attnout) {
  __shared__ __align__(16) u16 SM[24576];
  const int logical = (blockIdx.x & 7) * 512 + (blockIdx.x >> 3);   // 4096 blocks
  const int h = logical >> 8;           // 2 heads per XCD (bias/mod L2-resident)
  const int b = (logical >> 1) & 127;   // qpair-adjacent -> K/V L2 reuse
  const int qpair = logical & 1;
  const int tid = threadIdx.x, lane = tid & 63, w = tid >> 6;
  const int lr = lane & 15, lg = lane >> 4;
  const int rb = qpair * 8 + w;         // this wave's row-block (16 q rows)
  const int bhid = b * 16 + h;

  const u16* kg = kfrag + (size_t)bhid * 8192;
  const u16* vg = vsw + (size_t)bhid * 8192;
#pragma unroll
  for (int it = 0; it < 2; ++it) {
    __builtin_amdgcn_global_load_lds(AS1(kg + (it * 512 + tid) * 8),
                                     AS3(SM + (it * 512 + tid) * 8), 16, 0, 0);
    __builtin_amdgcn_global_load_lds(AS1(vg + (it * 512 + tid) * 8),
                                     AS3(SM + 8192 + (it * 512 + tid) * 8), 16, 0, 0);
  }
  bf16x8 qf = *(const bf16x8*)(qfrag + ((size_t)bhid * 16 + rb) * 512 + lane * 8);
  __syncthreads();

  const u16* bias_base = bias2 + (((size_t)h * 16 + rb) * 64 + lane) * 64;
  const u16* mod_base  = mod2 + ((size_t)rb * 64 + lane) * 64;
  char* Pbase = (char*)SM + 32768 + w * 2048;
  const char* Vb = (const char*)(SM + 8192);

  // S^T = K Q^T + bias : full 16 tiles, per-quarter transient bias loads
  f32x4 s[16];
#pragma unroll
  for (int q = 0; q < 4; ++q) {
    u32 bw8[8];
    {
      const uint4* bp = (const uint4*)(bias_base + q * 16);
      *(uint4*)&bw8[0] = bp[0]; *(uint4*)&bw8[4] = bp[1];
    }
    __builtin_amdgcn_s_setprio(1);   // T5: favor MFMA-issuing wave (independent waves)
#pragma unroll
    for (int tl = 0; tl < 4; ++tl) {
      int t = q * 4 + tl;
      bf16x8 kf = *(const bf16x8*)(SM + (t * 64 + lane) * 8);
      f32x4 c;
      c[0] = bf_lo(bw8[tl * 2]);     c[1] = bf_hi(bw8[tl * 2]);
      c[2] = bf_lo(bw8[tl * 2 + 1]); c[3] = bf_hi(bw8[tl * 2 + 1]);
      s[t] = __builtin_amdgcn_mfma_f32_16x16x32_bf16(kf, qf, c, 0, 0, 0);
    }
    __builtin_amdgcn_s_setprio(0);
  }

  // softmax over m (log2 domain): 4 parallel max chains + 2 shuffles
  float mr0 = s[0][0], mr1 = s[0][1], mr2 = s[0][2], mr3 = s[0][3];
#pragma unroll
  for (int t = 1; t < 16; ++t) {
    mr0 = fmaxf(mr0, s[t][0]); mr1 = fmaxf(mr1, s[t][1]);
    mr2 = fmaxf(mr2, s[t][2]); mr3 = fmaxf(mr3, s[t][3]);
  }
  float mx = fmaxf(fmaxf(mr0, mr1), fmaxf(mr2, mr3));
  mx = fmaxf(mx, __shfl_xor(mx, 16, 64));
  mx = fmaxf(mx, __shfl_xor(mx, 32, 64));
  float s0 = 0.f, s1 = 0.f, s2 = 0.f, s3 = 0.f;
#pragma unroll
  for (int t = 0; t < 16; ++t) {
    s[t][0] = ex2(s[t][0] - mx); s0 += s[t][0];
    s[t][1] = ex2(s[t][1] - mx); s1 += s[t][1];
    s[t][2] = ex2(s[t][2] - mx); s2 += s[t][2];
    s[t][3] = ex2(s[t][3] - mx); s3 += s[t][3];
  }
  float sm = (s0 + s1) + (s2 + s3);
  sm += __shfl_xor(sm, 16, 64);
  sm += __shfl_xor(sm, 32, 64);
  sm = __builtin_amdgcn_rcpf(sm);   // own-lane: denominator for query n = lr (pre-pack norm)

  // quarter-partitioned pack (normalized P, mod applied) + PV
  f32x4 o0 = (f32x4){0.f, 0.f, 0.f, 0.f};
  f32x4 o1 = (f32x4){0.f, 0.f, 0.f, 0.f};
#pragma unroll
  for (int q = 0; q < 4; ++q) {
    u32 mw8[8];
    {
      const uint4* mp = (const uint4*)(mod_base + q * 16);
      *(uint4*)&mw8[0] = mp[0]; *(uint4*)&mw8[4] = mp[1];
    }
#pragma unroll
    for (int tl = 0; tl < 4; ++tl) {
      int t = q * 4 + tl;
      u16 pk[4];
#pragma unroll
      for (int r = 0; r < 4; ++r) {
        u32 wd = mw8[tl * 2 + (r >> 1)];
        float mf = (r & 1) ? bf_hi(wd) : bf_lo(wd);
        pk[r] = f2bc(s[t][r] * sm * mf);
      }
      int hi2 = (t * 2 + (lg >> 1)) & 3;
      *(uint2*)(Pbase + ((t >> 1) & 1) * 1024 + ((hi2 << 4) | lr) * 16 + (lg & 1) * 8)
          = *(const uint2*)pk;
    }
    asm volatile("" ::: "memory");   // pack stores must precede PV loads
    __builtin_amdgcn_s_setprio(1);   // T5
#pragma unroll
    for (int kl = 0; kl < 2; ++kl) {
      bf16x8 pa = *(const bf16x8*)(Pbase + kl * 1024 + lane * 16);
      int cv = ((q * 2 + kl) * 4 + lg) ^ (lr & 7);
      bf16x8 v0 = *(const bf16x8*)(Vb + lr * 512 + cv * 16);
      bf16x8 v1 = *(const bf16x8*)(Vb + (16 + lr) * 512 + cv * 16);
      o0 = __builtin_amdgcn_mfma_f32_16x16x32_bf16(pa, v0, o0, 0, 0, 0);
      o1 = __builtin_amdgcn_mfma_f32_16x16x32_bf16(pa, v1, o1, 0, 0, 0);
    }
    __builtin_amdgcn_s_setprio(0);
    asm volatile("" ::: "memory");   // PV loads must precede next quarter's pack (WAR)
  }

  // O-store bounce through dead P region: lg-XOR-swizzled 1KB/wave tile,
  // then one coalesced 16B store per lane (replaces 8 scattered u16 stores).
  u16* Ob = (u16*)Pbase;
#pragma unroll
  for (int r = 0; r < 4; ++r) {
    int row = lg * 4 + r;
    int gs0 = (lr >> 3) ^ lg;              // granule of d = lr
    int gs1 = (2 + (lr >> 3)) ^ lg;        // granule of d = 16+lr
    *(u16*)((char*)Ob + row * 64 + gs0 * 16 + (lr & 7) * 2) = f2bc(o0[r]);
    *(u16*)((char*)Ob + row * 64 + gs1 * 16 + (lr & 7) * 2) = f2bc(o1[r]);
  }
  asm volatile("" ::: "memory");   // O writes must precede readback
  {
    int row = lane >> 2, c = lane & 3;     // writer lg = row>>2 -> un-swizzle c^(row>>2)
    uint4 v = *(const uint4*)((const char*)Ob + row * 64 + ((c ^ (row >> 2)) << 4));
    u16* orow = attnout + (size_t)(b * TOK + rb * 16 + row) * CDIM + h * 32 + c * 8;
    *(uint4*)orow = v;
  }
}

// ---------------- launch ----------------
extern "C" void kernel_launch(void* const* d_in, const int* in_sizes, int n_in,
                              void* d_out, int out_size, void* d_ws, size_t ws_size,
                              hipStream_t stream) {
  const float* x      = (const float*)d_in[0];
  const float* qkv_w  = (const float*)d_in[1];
  const float* qkv_b  = (const float*)d_in[2];
  const float* proj_w = (const float*)d_in[3];
  const float* proj_b = (const float*)d_in[4];
  const float* rpb    = (const float*)d_in[5];

  char* ws = (char*)d_ws;
  u16* qkvwb  = (u16*)(ws + 33554432);      //  1,572,864 B
  u16* projwb = (u16*)(ws + 35127296);      //    524,288 B
  u16* qfrag  = (u16*)(ws + 35651584);      // 33,554,432 B
  u16* kfrag  = (u16*)(ws + 69206016);      // 33,554,432 B
  u16* vswb   = (u16*)(ws + 102760448);     // 33,554,432 B
  u16* attnb  = (u16*)(ws + 136314880);     // 33,554,432 B
  u16* bias2  = (u16*)(ws + 169869312);     //  2,097,152 B
  u16* mod2   = (u16*)(ws + 171966464);     //    131,072 B

  prep_kernel<<<4864, 256, 0, stream>>>(qkv_w, proj_w, rpb, qkvwb, projwb, bias2, mod2);
  gemm_bt<0><<<1536, 512, 0, stream>>>(x, nullptr, qkvwb, qkv_b,
                                       qfrag, kfrag, vswb, nullptr);
  attn_kernel<<<4096, 512, 0, stream>>>(qfrag, kfrag, vswb, bias2, mod2, attnb);
  gemm_bt<1><<<1024, 256, 0, stream>>>(nullptr, attnb, projwb, proj_b,
                                       nullptr, nullptr, nullptr, (float*)d_out);
}

// Round 21
// 200.327 us; speedup vs baseline: 1.0960x; 1.0960x over previous
//
#include <hip/hip_runtime.h>
#include <hip/hip_bf16.h>

typedef unsigned short u16;
typedef unsigned int u32;
typedef __bf16 bf16x8 __attribute__((ext_vector_type(8)));
typedef float f32x4 __attribute__((ext_vector_type(4)));

#define AS1(p) ((const __attribute__((address_space(1))) void*)(p))
#define AS3(p) ((__attribute__((address_space(3))) void*)(p))

#define TOK   256
#define CDIM  512
#define QKVC  1536
#define LOG2E 1.4426950408889634f
#define QSCALE (0.17677669529663687f * 1.4426950408889634f)  // D^-0.5 * log2e

__device__ __forceinline__ u16 f2b(float f) {
  unsigned u = __float_as_uint(f);
  unsigned r = (u + 0x7fffu + ((u >> 16) & 1u)) >> 16;
  return (u16)r;
}
__device__ __forceinline__ u16 f2bc(float f) {
  __bf16 h = (__bf16)f;
  u16 u;
  __builtin_memcpy(&u, &h, 2);
  return u;
}
__device__ __forceinline__ float bf_lo(u32 wd) { return __uint_as_float(wd << 16); }
__device__ __forceinline__ float bf_hi(u32 wd) { return __uint_as_float(wd & 0xffff0000u); }
__device__ __forceinline__ float ex2(float x) {
  float r;
  asm("v_exp_f32 %0, %1" : "=v"(r) : "v"(x));
  return r;
}

// ---------------- fused preamble: weight cvt + bias2 + mod2 tables ----------------
__global__ __launch_bounds__(256) void prep_kernel(const float* __restrict__ qkv_w,
                                                   const float* __restrict__ proj_w,
                                                   const float* __restrict__ rpb,
                                                   u16* __restrict__ qkvwb,
                                                   u16* __restrict__ projwb,
                                                   u16* __restrict__ bias2,
                                                   u16* __restrict__ mod2) {
  const int blk = blockIdx.x, tid = threadIdx.x;
  if (blk < 512) {
    const float* in = (blk < 384) ? qkv_w : proj_w;
    u16* out = (blk < 384) ? qkvwb : projwb;
    int base = (blk < 384) ? blk : (blk - 384);
    int i = (base * 256 + tid) * 8;
    float4 a = *(const float4*)(in + i);
    float4 b = *(const float4*)(in + i + 4);
    u16 h[8];
    h[0] = f2b(a.x); h[1] = f2b(a.y); h[2] = f2b(a.z); h[3] = f2b(a.w);
    h[4] = f2b(b.x); h[5] = f2b(b.y); h[6] = f2b(b.z); h[7] = f2b(b.w);
    *(uint4*)(out + i) = *(const uint4*)h;
  } else if (blk < 4608) {
    int i = (blk - 512) * 256 + tid;   // 16*16*64*64 = 2^20
    int tr = i & 63, lane = (i >> 6) & 63, rb = (i >> 12) & 15, h = i >> 16;
    int t = tr >> 2, r = tr & 3;
    int n = rb * 16 + (lane & 15);
    int m = t * 16 + (lane >> 4) * 4 + r;
    int idx = ((n >> 4) - (m >> 4) + 15) * 31 + ((n & 15) - (m & 15) + 15);
    bias2[i] = f2b(rpb[idx * 16 + h] * LOG2E);
  } else {
    int i = (blk - 4608) * 256 + tid;  // 16*64*64 = 65536
    int tr = i & 63, lane = (i >> 6) & 63, rb = i >> 12;
    int t = tr >> 2, r = tr & 3;
    int n = rb * 16 + (lane & 15);
    int m = t * 16 + (lane >> 4) * 4 + r;
    int dr = (n >> 4) - (m >> 4), dc = (n & 15) - (m & 15);
    int d2 = dr * dr + dc * dc;
    float val = 0.0f;
    if (d2 <= 229) {   // exact integer form of (m >= bound); boundary at d2==229
      const float fc = 6.2831853071795864f / (60.0f * 1.4142135623730951f);
      val = expf(cosf(fc * sqrtf((float)d2))) * 0.5f;
    }
    mod2[i] = f2b(val);
  }
}

// ---------------- bf16 GEMM: out = A[M,K] @ Bt[N,K]^T + bias ----------------
// MODE 0: BM=256, 512 thr, A = x (fp32, converted in reg-staging); LDS-bounce epilogue
//         -> qfrag (scaled) / kfrag / vsw, fragment-ordered bf16.
// MODE 1: BM=128, 256 thr, A = attnb (bf16, gload_lds); f32 out (nontemporal).
template<int MODE>
__global__ __launch_bounds__(MODE == 0 ? 512 : 256) void gemm_bt(
    const float* __restrict__ Ax, const u16* __restrict__ A,
    const u16* __restrict__ Bt, const float* __restrict__ bvec,
    u16* __restrict__ oq, u16* __restrict__ ok, u16* __restrict__ ov,
    float* __restrict__ of) {
  constexpr int K = 512;
  constexpr int BM = (MODE == 0) ? 256 : 128;
  constexpr int NT = (MODE == 0) ? 512 : 256;
  constexpr int NBN = (MODE == 0) ? 12 : 4;
  constexpr int PER_XCD = (MODE == 0) ? 192 : 128;
  __shared__ __align__(16) u16 SM[(MODE == 0) ? 32768 : 16384];
  u16* As = SM;
  u16* Bs = SM + BM * 64;
  const int tid = threadIdx.x, lane = tid & 63, w = tid >> 6;
  const int wr = w >> 1, wc = w & 1, lr = lane & 15, lg = lane >> 4;
  // XCD-chunked 1-D grid: bm-pair x all-bn contiguous per XCD (A+B L2-resident)
  const int logical = (blockIdx.x & 7) * PER_XCD + (blockIdx.x >> 3);
  const int bm = (logical / (2 * NBN)) * 2 + (logical & 1);
  const int bn = (logical % (2 * NBN)) >> 1;
  const u16* Bg = Bt + (size_t)bn * 128 * K;
  f32x4 acc[4][4];
#pragma unroll
  for (int m = 0; m < 4; ++m)
#pragma unroll
    for (int n = 0; n < 4; ++n) acc[m][n] = (f32x4){0.f, 0.f, 0.f, 0.f};

  for (int k0 = 0; k0 < K; k0 += 64) {
    if (MODE == 0) {
      // A: reg-stage fp32 x -> cvt -> swizzled ds_write (slot kc holds granule kc^(r&7))
#pragma unroll
      for (int it = 0; it < 4; ++it) {
        int chunk = it * NT + tid;            // (r, kc): r = chunk>>3, kc = chunk&7
        int r = chunk >> 3, kc = chunk & 7;
        int gg = kc ^ (r & 7);                // global granule for this LDS slot
        const float* src = Ax + (size_t)(bm * 256 + r) * K + k0 + gg * 8;
        float4 v0 = *(const float4*)src;
        float4 v1 = *(const float4*)(src + 4);
        u16 hb[8];
        hb[0] = f2bc(v0.x); hb[1] = f2bc(v0.y); hb[2] = f2bc(v0.z); hb[3] = f2bc(v0.w);
        hb[4] = f2bc(v1.x); hb[5] = f2bc(v1.y); hb[6] = f2bc(v1.z); hb[7] = f2bc(v1.w);
        *(uint4*)(As + chunk * 8) = *(const uint4*)hb;
      }
      // B: gload_lds with pre-swizzled source granule
#pragma unroll
      for (int it = 0; it < 2; ++it) {
        int chunk = it * NT + tid;
        int r = chunk >> 3, kc = chunk & 7;
        int kcs = kc ^ (r & 7);
        __builtin_amdgcn_global_load_lds(AS1(Bg + (size_t)r * K + k0 + kcs * 8),
                                         AS3(Bs + chunk * 8), 16, 0, 0);
      }
    } else {
      const u16* Ag = A + (size_t)bm * 128 * K;
#pragma unroll
      for (int it = 0; it < 4; ++it) {
        int chunk = it * NT + tid;
        int r = chunk >> 3, kc = chunk & 7;
        int kcs = kc ^ (r & 7);
        __builtin_amdgcn_global_load_lds(AS1(Ag + (size_t)r * K + k0 + kcs * 8),
                                         AS3(As + chunk * 8), 16, 0, 0);
        __builtin_amdgcn_global_load_lds(AS1(Bg + (size_t)r * K + k0 + kcs * 8),
                                         AS3(Bs + chunk * 8), 16, 0, 0);
      }
    }
    __syncthreads();
#pragma unroll
    for (int kk = 0; kk < 2; ++kk) {
      bf16x8 a[4], b[4];
#pragma unroll
      for (int m = 0; m < 4; ++m) {
        int ar = wr * 64 + m * 16 + lr;
        a[m] = *(const bf16x8*)&As[ar * 64 + (((kk * 4 + lg) ^ (lr & 7)) << 3)];
      }
#pragma unroll
      for (int n = 0; n < 4; ++n) {
        int br = wc * 64 + n * 16 + lr;
        b[n] = *(const bf16x8*)&Bs[br * 64 + (((kk * 4 + lg) ^ (lr & 7)) << 3)];
      }
#pragma unroll
      for (int m = 0; m < 4; ++m)
#pragma unroll
        for (int n = 0; n < 4; ++n)
          acc[m][n] = __builtin_amdgcn_mfma_f32_16x16x32_bf16(a[m], b[n], acc[m][n], 0, 0, 0);
    }
    __syncthreads();
  }

  if (MODE == 1) {
#pragma unroll
    for (int m = 0; m < 4; ++m)
#pragma unroll
      for (int n = 0; n < 4; ++n)
#pragma unroll
        for (int r = 0; r < 4; ++r) {
          int row = bm * BM + wr * 64 + m * 16 + lg * 4 + r;
          int col = bn * 128 + wc * 64 + n * 16 + lr;
          __builtin_nontemporal_store(acc[m][n][r] + bvec[col],
                                      &of[(size_t)row * CDIM + col]);
        }
    return;
  }

  // ---- MODE 0 epilogue: bounce via per-wave swizzled 64x64 bf16 LDS tile ----
  const int typ = bn >> 2;                 // 0=Q, 1=K, 2=V
  const int col0 = bn * 128 + wc * 64;
  const int row0 = bm * 256 + wr * 64;
  char* Tb = (char*)SM + w * 8192;         // 8 KB per wave (staging region is dead)

#pragma unroll
  for (int n = 0; n < 4; ++n) {
    float bv = bvec[col0 + n * 16 + lr];
#pragma unroll
    for (int m = 0; m < 4; ++m)
#pragma unroll
      for (int r = 0; r < 4; ++r) {
        float v = acc[m][n][r] + bv;
        if (typ == 0) v *= QSCALE;
        int row_l, col_l;
        if (typ < 2) { row_l = m * 16 + lg * 4 + r; col_l = n * 16 + lr; }
        else         { row_l = n * 16 + lr;         col_l = m * 16 + lg * 4 + r; }  // V: transposed
        int byte = row_l * 128 + ((((col_l >> 3) ^ (row_l & 7)) << 4) | ((col_l & 7) << 1));
        *(u16*)(Tb + byte) = f2b(v);
      }
  }
  asm volatile("" ::: "memory");   // pin LDS write->read order (strict-aliasing guard)
  // wave-local tile: DS pipe is in-order within a wave; no barrier needed
  if (typ < 2) {
    // Q/K readback: lane = token row; 8 x {ds_read_b128, coalesced 16B store}
    int tok = row0 + lane;
    int tokb = tok >> 8;
    u16* obase = (typ == 0) ? oq : ok;
#pragma unroll
    for (int G = 0; G < 8; ++G) {
      int hl = G >> 2, q = G & 3;
      uint4 v = *(const uint4*)(Tb + lane * 128 + ((G ^ (lane & 7)) << 4));
      int hh = ((col0 >> 5) & 15) + hl;     // head index
      size_t a = ((((size_t)tokb * 16 + hh) * 16 + ((tok >> 4) & 15)) * 64 +
                  ((tok & 15) | (q << 4))) * 8;
      *(uint4*)(obase + a) = v;
    }
  } else {
    // V readback: transposed tile; swizzles cancel -> sequential granules
    int tl0 = row0 & 255, tokb = row0 >> 8;
    int hl = lane >> 5, t = (lane >> 3) & 3, c = lane & 7;
    int hh = ((col0 >> 5) & 15) + hl;       // head index
#pragma unroll
    for (int i = 0; i < 8; ++i) {
      int d = i * 4 + t;
      uint4 v = *(const uint4*)(Tb + (hl * 32 + d) * 128 + (c << 4));
      size_t a = (((size_t)tokb * 16 + hh) * 32 + d) * 256 + tl0 + c * 8;
      *(uint4*)(ov + a) = v;
    }
  }
}

// ---------------- fused attention: 512-thread block = (b, h, qpair), 8 waves ----------------
__global__ __launch_bounds__(512, 4) void attn_kernel(const u16* __restrict__ qfrag,
                                                      const u16* __restrict__ kfrag,
                                                      const u16* __restrict__ vsw,
                                                      const u16* __restrict__ bias2,
                                                      const u16* __restrict__ mod2,
                                                      u16* __restrict__ attnout) {
  __shared__ __align__(16) u16 SM[24576];
  const int logical = (blockIdx.x & 7) * 512 + (blockIdx.x >> 3);   // 4096 blocks
  const int h = logical >> 8;           // 2 heads per XCD (bias/mod L2-resident)
  const int b = (logical >> 1) & 127;   // qpair-adjacent -> K/V L2 reuse
  const int qpair = logical & 1;
  const int tid = threadIdx.x, lane = tid & 63, w = tid >> 6;
  const int lr = lane & 15, lg = lane >> 4;
  const int rb = qpair * 8 + w;         // this wave's row-block (16 q rows)
  const int bhid = b * 16 + h;

  const u16* kg = kfrag + (size_t)bhid * 8192;
  const u16* vg = vsw + (size_t)bhid * 8192;
#pragma unroll
  for (int it = 0; it < 2; ++it) {
    __builtin_amdgcn_global_load_lds(AS1(kg + (it * 512 + tid) * 8),
                                     AS3(SM + (it * 512 + tid) * 8), 16, 0, 0);
    __builtin_amdgcn_global_load_lds(AS1(vg + (it * 512 + tid) * 8),
                                     AS3(SM + 8192 + (it * 512 + tid) * 8), 16, 0, 0);
  }
  bf16x8 qf = *(const bf16x8*)(qfrag + ((size_t)bhid * 16 + rb) * 512 + lane * 8);
  __syncthreads();

  const u16* bias_base = bias2 + (((size_t)h * 16 + rb) * 64 + lane) * 64;
  const u16* mod_base  = mod2 + ((size_t)rb * 64 + lane) * 64;
  char* Pbase = (char*)SM + 32768 + w * 2048;
  const char* Vb = (const char*)(SM + 8192);

  // S^T = K Q^T + bias : full 16 tiles, per-quarter transient bias loads
  f32x4 s[16];
#pragma unroll
  for (int q = 0; q < 4; ++q) {
    u32 bw8[8];
    {
      const uint4* bp = (const uint4*)(bias_base + q * 16);
      *(uint4*)&bw8[0] = bp[0]; *(uint4*)&bw8[4] = bp[1];
    }
    __builtin_amdgcn_s_setprio(1);   // T5: favor MFMA-issuing wave (independent waves)
#pragma unroll
    for (int tl = 0; tl < 4; ++tl) {
      int t = q * 4 + tl;
      bf16x8 kf = *(const bf16x8*)(SM + (t * 64 + lane) * 8);
      f32x4 c;
      c[0] = bf_lo(bw8[tl * 2]);     c[1] = bf_hi(bw8[tl * 2]);
      c[2] = bf_lo(bw8[tl * 2 + 1]); c[3] = bf_hi(bw8[tl * 2 + 1]);
      s[t] = __builtin_amdgcn_mfma_f32_16x16x32_bf16(kf, qf, c, 0, 0, 0);
    }
    __builtin_amdgcn_s_setprio(0);
  }

  // softmax over m (log2 domain): 4 parallel max chains + 2 shuffles
  float mr0 = s[0][0], mr1 = s[0][1], mr2 = s[0][2], mr3 = s[0][3];
#pragma unroll
  for (int t = 1; t < 16; ++t) {
    mr0 = fmaxf(mr0, s[t][0]); mr1 = fmaxf(mr1, s[t][1]);
    mr2 = fmaxf(mr2, s[t][2]); mr3 = fmaxf(mr3, s[t][3]);
  }
  float mx = fmaxf(fmaxf(mr0, mr1), fmaxf(mr2, mr3));
  mx = fmaxf(mx, __shfl_xor(mx, 16, 64));
  mx = fmaxf(mx, __shfl_xor(mx, 32, 64));
  float s0 = 0.f, s1 = 0.f, s2 = 0.f, s3 = 0.f;
#pragma unroll
  for (int t = 0; t < 16; ++t) {
    s[t][0] = ex2(s[t][0] - mx); s0 += s[t][0];
    s[t][1] = ex2(s[t][1] - mx); s1 += s[t][1];
    s[t][2] = ex2(s[t][2] - mx); s2 += s[t][2];
    s[t][3] = ex2(s[t][3] - mx); s3 += s[t][3];
  }
  float sm = (s0 + s1) + (s2 + s3);
  sm += __shfl_xor(sm, 16, 64);
  sm += __shfl_xor(sm, 32, 64);
  sm = __builtin_amdgcn_rcpf(sm);   // own-lane: denominator for query n = lr (pre-pack norm)

  // quarter-partitioned pack (normalized P, mod applied) + PV
  f32x4 o0 = (f32x4){0.f, 0.f, 0.f, 0.f};
  f32x4 o1 = (f32x4){0.f, 0.f, 0.f, 0.f};
#pragma unroll
  for (int q = 0; q < 4; ++q) {
    u32 mw8[8];
    {
      const uint4* mp = (const uint4*)(mod_base + q * 16);
      *(uint4*)&mw8[0] = mp[0]; *(uint4*)&mw8[4] = mp[1];
    }
#pragma unroll
    for (int tl = 0; tl < 4; ++tl) {
      int t = q * 4 + tl;
      u16 pk[4];
#pragma unroll
      for (int r = 0; r < 4; ++r) {
        u32 wd = mw8[tl * 2 + (r >> 1)];
        float mf = (r & 1) ? bf_hi(wd) : bf_lo(wd);
        pk[r] = f2bc(s[t][r] * sm * mf);
      }
      int hi2 = (t * 2 + (lg >> 1)) & 3;
      *(uint2*)(Pbase + ((t >> 1) & 1) * 1024 + ((hi2 << 4) | lr) * 16 + (lg & 1) * 8)
          = *(const uint2*)pk;
    }
    asm volatile("" ::: "memory");   // pack stores must precede PV loads
    __builtin_amdgcn_s_setprio(1);   // T5
#pragma unroll
    for (int kl = 0; kl < 2; ++kl) {
      bf16x8 pa = *(const bf16x8*)(Pbase + kl * 1024 + lane * 16);
      int cv = ((q * 2 + kl) * 4 + lg) ^ (lr & 7);
      bf16x8 v0 = *(const bf16x8*)(Vb + lr * 512 + cv * 16);
      bf16x8 v1 = *(const bf16x8*)(Vb + (16 + lr) * 512 + cv * 16);
      o0 = __builtin_amdgcn_mfma_f32_16x16x32_bf16(pa, v0, o0, 0, 0, 0);
      o1 = __builtin_amdgcn_mfma_f32_16x16x32_bf16(pa, v1, o1, 0, 0, 0);
    }
    __builtin_amdgcn_s_setprio(0);
    asm volatile("" ::: "memory");   // PV loads must precede next quarter's pack (WAR)
  }

  // O-store bounce through dead P region: lg-XOR-swizzled 1KB/wave tile,
  // then one coalesced 16B store per lane (replaces 8 scattered u16 stores).
  u16* Ob = (u16*)Pbase;
#pragma unroll
  for (int r = 0; r < 4; ++r) {
    int row = lg * 4 + r;
    int gs0 = (lr >> 3) ^ lg;              // granule of d = lr
    int gs1 = (2 + (lr >> 3)) ^ lg;        // granule of d = 16+lr
    *(u16*)((char*)Ob + row * 64 + gs0 * 16 + (lr & 7) * 2) = f2bc(o0[r]);
    *(u16*)((char*)Ob + row * 64 + gs1 * 16 + (lr & 7) * 2) = f2bc(o1[r]);
  }
  asm volatile("" ::: "memory");   // O writes must precede readback
  {
    int row = lane >> 2, c = lane & 3;     // writer lg = row>>2 -> un-swizzle c^(row>>2)
    uint4 v = *(const uint4*)((const char*)Ob + row * 64 + ((c ^ (row >> 2)) << 4));
    u16* orow = attnout + (size_t)(b * TOK + rb * 16 + row) * CDIM + h * 32 + c * 8;
    *(uint4*)orow = v;
  }
}

// ---------------- launch ----------------
extern "C" void kernel_launch(void* const* d_in, const int* in_sizes, int n_in,
                              void* d_out, int out_size, void* d_ws, size_t ws_size,
                              hipStream_t stream) {
  const float* x      = (const float*)d_in[0];
  const float* qkv_w  = (const float*)d_in[1];
  const float* qkv_b  = (const float*)d_in[2];
  const float* proj_w = (const float*)d_in[3];
  const float* proj_b = (const float*)d_in[4];
  const float* rpb    = (const float*)d_in[5];

  char* ws = (char*)d_ws;
  u16* qkvwb  = (u16*)(ws + 33554432);      //  1,572,864 B
  u16* projwb = (u16*)(ws + 35127296);      //    524,288 B
  u16* qfrag  = (u16*)(ws + 35651584);      // 33,554,432 B
  u16* kfrag  = (u16*)(ws + 69206016);      // 33,554,432 B
  u16* vswb   = (u16*)(ws + 102760448);     // 33,554,432 B
  u16* attnb  = (u16*)(ws + 136314880);     // 33,554,432 B
  u16* bias2  = (u16*)(ws + 169869312);     //  2,097,152 B
  u16* mod2   = (u16*)(ws + 171966464);     //    131,072 B

  prep_kernel<<<4864, 256, 0, stream>>>(qkv_w, proj_w, rpb, qkvwb, projwb, bias2, mod2);
  gemm_bt<0><<<1536, 512, 0, stream>>>(x, nullptr, qkvwb, qkv_b,
                                       qfrag, kfrag, vswb, nullptr);
  attn_kernel<<<4096, 512, 0, stream>>>(qfrag, kfrag, vswb, bias2, mod2, attnb);
  gemm_bt<1><<<1024, 256, 0, stream>>>(nullptr, attnb, projwb, proj_b,
                                       nullptr, nullptr, nullptr, (float*)d_out);
}